// Round 1
// baseline (10.968 us; speedup 1.0000x reference)
//
#include <hip/hip_runtime.h>

// DualReLU bound-propagation scatter.
// For each sparse row r: b=batch_idx[r], n=neuron_idx[r],
//   v = d_next[b,n] * d_vals[r]
//   v<0 -> zl[b,n] += zlI[r]*(-v)   ; v>0 -> zu[b,n] += -(zlI[r]*v)
// Both branches add (-zlI[r]*v) to the chosen output plane.
// Output layout: d_out[0:B*N] = zl, d_out[B*N:2*B*N] = zu.
//
// batch_idx is sorted -> one block per batch, LDS accumulation, no global
// atomics and no separate zero-fill kernel (each block writes its full slice).

__global__ __launch_bounds__(1024) void dualrelu_scatter_kernel(
    const int*   __restrict__ batch_idx,
    const int*   __restrict__ neuron_idx,
    const float* __restrict__ d_vals,
    const float* __restrict__ d_next,
    const float* __restrict__ zlI,
    float*       __restrict__ out,
    int K, int B, int N)
{
    extern __shared__ float lds[];       // [2*N] : zl then zu
    float* zl = lds;
    float* zu = lds + N;

    const int b    = blockIdx.x;
    const int tid  = threadIdx.x;
    const int nthr = blockDim.x;

    // zero LDS accumulators
    for (int i = tid; i < 2 * N; i += nthr) lds[i] = 0.0f;

    // segment bounds [lo, hi) for batch b via binary search (uniform per block)
    int lo, hi;
    {
        int l = 0, r = K;
        while (l < r) { int m = (l + r) >> 1; if (batch_idx[m] < b)     l = m + 1; else r = m; }
        lo = l;
        r = K;
        while (l < r) { int m = (l + r) >> 1; if (batch_idx[m] < b + 1) l = m + 1; else r = m; }
        hi = l;
    }
    __syncthreads();

    const float* __restrict__ drow = d_next + (size_t)b * N;

    for (int r = lo + tid; r < hi; r += nthr) {
        int   n = neuron_idx[r];
        float v = drow[n] * d_vals[r];
        float add = -zlI[r] * v;
        if (v < 0.0f)      atomicAdd(&zl[n], add);
        else if (v > 0.0f) atomicAdd(&zu[n], add);
    }
    __syncthreads();

    // write out full slice for this batch (coalesced); covers zeros too
    float* __restrict__ outzl = out + (size_t)b * N;
    float* __restrict__ outzu = out + (size_t)(B + b) * N;
    for (int i = tid; i < N; i += nthr) {
        outzl[i] = zl[i];
        outzu[i] = zu[i];
    }
}

extern "C" void kernel_launch(void* const* d_in, const int* in_sizes, int n_in,
                              void* d_out, int out_size, void* d_ws, size_t ws_size,
                              hipStream_t stream) {
    const int*   batch_idx  = (const int*)  d_in[0];
    const int*   neuron_idx = (const int*)  d_in[1];
    const float* d_vals     = (const float*)d_in[2];
    const float* d_next     = (const float*)d_in[3];
    const float* zlI        = (const float*)d_in[4];
    float*       out        = (float*)d_out;

    const int K = in_sizes[0];          // 32768
    const int B = 32;                   // reference constant
    const int N = in_sizes[3] / B;      // 2048

    dim3 grid(B), block(1024);
    size_t lds_bytes = (size_t)2 * N * sizeof(float);
    dualrelu_scatter_kernel<<<grid, block, lds_bytes, stream>>>(
        batch_idx, neuron_idx, d_vals, d_next, zlI, out, K, B, N);
}

// Round 2
// 10.257 us; speedup vs baseline: 1.0693x; 1.0693x over previous
//
#include <hip/hip_runtime.h>

// DualReLU bound-propagation scatter.
// For each sparse row r: b=batch_idx[r], n=neuron_idx[r],
//   v = d_next[b,n] * d_vals[r]
//   v<0 -> zl[b,n] += -zlI[r]*v ; v>0 -> zu[b,n] += -zlI[r]*v
// Output layout: d_out[0:B*N] = zl, d_out[B*N:2*B*N] = zu.
//
// One block per batch. No binary search (it was ~30 DEPENDENT global loads,
// a multi-microsecond serial latency chain): instead each block scans all K
// rows in a fully parallel strided loop and filters on batch_idx[r]==b.
// batch_idx is sorted, so the filter predicate is wave-uniform except at
// segment boundaries -> negligible divergence; re-reads are L2-resident.

__global__ __launch_bounds__(1024) void dualrelu_scatter_kernel(
    const int*   __restrict__ batch_idx,
    const int*   __restrict__ neuron_idx,
    const float* __restrict__ d_vals,
    const float* __restrict__ d_next,
    const float* __restrict__ zlI,
    float*       __restrict__ out,
    int K, int B, int N)
{
    extern __shared__ float lds[];       // [2*N] : zl then zu
    float* zl = lds;
    float* zu = lds + N;

    const int b    = blockIdx.x;
    const int tid  = threadIdx.x;
    const int nthr = blockDim.x;

    // zero LDS accumulators
    for (int i = tid; i < 2 * N; i += nthr) lds[i] = 0.0f;
    __syncthreads();

    const float* __restrict__ drow = d_next + (size_t)b * N;

    // vectorized scan: each thread inspects 4 consecutive rows per iteration
    const int K4 = K >> 2;               // K % 4 == 0 (K = 32768)
    const int4* __restrict__ bidx4 = (const int4*)batch_idx;
    for (int q = tid; q < K4; q += nthr) {
        int4 bi = bidx4[q];
        int base = q << 2;
        #pragma unroll
        for (int j = 0; j < 4; ++j) {
            int bij = (j == 0) ? bi.x : (j == 1) ? bi.y : (j == 2) ? bi.z : bi.w;
            if (bij == b) {
                int   r = base + j;
                int   n = neuron_idx[r];
                float v = drow[n] * d_vals[r];
                float add = -zlI[r] * v;
                if (v < 0.0f)      atomicAdd(&zl[n], add);
                else if (v > 0.0f) atomicAdd(&zu[n], add);
            }
        }
    }
    __syncthreads();

    // write out full slice for this batch (coalesced, vectorized);
    // covers zeros too, so no separate output zero-fill is needed
    float2* __restrict__ outzl = (float2*)(out + (size_t)b * N);
    float2* __restrict__ outzu = (float2*)(out + (size_t)(B + b) * N);
    const float2* __restrict__ zl2 = (const float2*)zl;
    const float2* __restrict__ zu2 = (const float2*)zu;
    const int N2 = N >> 1;
    for (int i = tid; i < N2; i += nthr) {
        outzl[i] = zl2[i];
        outzu[i] = zu2[i];
    }
}

extern "C" void kernel_launch(void* const* d_in, const int* in_sizes, int n_in,
                              void* d_out, int out_size, void* d_ws, size_t ws_size,
                              hipStream_t stream) {
    const int*   batch_idx  = (const int*)  d_in[0];
    const int*   neuron_idx = (const int*)  d_in[1];
    const float* d_vals     = (const float*)d_in[2];
    const float* d_next     = (const float*)d_in[3];
    const float* zlI        = (const float*)d_in[4];
    float*       out        = (float*)d_out;

    const int K = in_sizes[0];          // 32768
    const int B = 32;                   // reference constant
    const int N = in_sizes[3] / B;      // 2048

    dim3 grid(B), block(1024);
    size_t lds_bytes = (size_t)2 * N * sizeof(float);
    dualrelu_scatter_kernel<<<grid, block, lds_bytes, stream>>>(
        batch_idx, neuron_idx, d_vals, d_next, zlI, out, K, B, N);
}

// Round 3
// 9.609 us; speedup vs baseline: 1.1414x; 1.0674x over previous
//
#include <hip/hip_runtime.h>
#include <limits.h>

// DualReLU bound-propagation scatter, latency-optimized.
// For each sparse row r: b=batch_idx[r], n=neuron_idx[r],
//   v = d_next[b,n] * d_vals[r]; add = -zlI[r]*v
//   v<0 -> zl[b,n] += add ; v>0 -> zu[b,n] += add
// Output: d_out[0:B*N] = zl, d_out[B*N:2*B*N] = zu.
//
// One block per batch. Instead of scanning all K rows (128KB/block, round 2)
// or a serial binary search (round 1), find the segment bounds with TWO
// parallel load rounds:
//   round 1: 1024 probes at stride S=K/1024 (all threads, 1 load each)
//            + concurrently stage d_next row b into LDS (independent loads)
//   round 2: 2 waves refine the lo/hi windows (<=S wide) with 2 loads/lane
// Then one coalesced round over the ~1024-row segment, LDS-gather of d_next,
// LDS atomic scatter, and a full-slice vectorized write (covers zeros).

#define NTHR 1024

__global__ __launch_bounds__(NTHR) void dualrelu_kernel(
    const int*   __restrict__ batch_idx,
    const int*   __restrict__ neuron_idx,
    const float* __restrict__ d_vals,
    const float* __restrict__ d_next,
    const float* __restrict__ zlI,
    float*       __restrict__ out,
    int K, int B, int N, int S)
{
    extern __shared__ char smem[];
    float* drow   = (float*)smem;          // N floats: staged d_next row
    float* zl     = drow + N;              // N floats
    float* zu     = zl + N;                // N floats (contiguous with zl)
    int*   probes = (int*)(zu + N);        // NTHR ints
    int*   ctrl   = probes + NTHR;         // [0]=wlo [1]=whi [2]=lo [3]=hi

    const int b   = blockIdx.x;
    const int tid = threadIdx.x;

    // ---- round 1: issue all independent global loads up front ----
    int ppos  = tid * S;
    int probe = (ppos < K) ? batch_idx[ppos] : INT_MAX;

    const int N2 = N >> 1;
    const float2* __restrict__ dg2 = (const float2*)(d_next + (size_t)b * N);
    float2* drow2 = (float2*)drow;

    // VALU/LDS work while loads are in flight
    if (tid == 0) { ctrl[0] = -1; ctrl[1] = -1; ctrl[2] = 0; ctrl[3] = 0; }
    for (int i = tid; i < 2 * N; i += NTHR) zl[i] = 0.0f;   // zl+zu contiguous

    for (int i = tid; i < N2; i += NTHR) drow2[i] = dg2[i]; // stage d_next row
    probes[tid] = probe;
    __syncthreads();

    // ---- window detect (LDS/VALU only) ----
    {
        int a = probes[tid];
        int c = (tid < NTHR - 1) ? probes[tid + 1] : INT_MAX;
        if (a < b     && c >= b    ) ctrl[0] = tid;   // lo in (tid*S, tid*S+S]
        if (a < b + 1 && c >= b + 1) ctrl[1] = tid;   // hi window
    }
    __syncthreads();

    // ---- round 2: refine windows (wave0 -> lo, wave1 -> hi) ----
    {
        int wave = tid >> 6;
        int lane = tid & 63;
        if (wave < 2) {
            int thr_v = b + wave;
            int w = ctrl[wave];
            if (w >= 0) {
                for (int j = lane; j < S; j += 64) {
                    int p  = w * S + 1 + j;
                    int v  = (p     < K) ? batch_idx[p]     : INT_MAX;
                    int pv = (p - 1 < K) ? batch_idx[p - 1] : INT_MAX;
                    if (pv < thr_v && v >= thr_v) ctrl[2 + wave] = p;
                }
            }
            // w == -1 means probes[0] >= thr_v -> bound = 0 (default)
        }
    }
    __syncthreads();

    const int lo = ctrl[2];
    const int hi = ctrl[3];

    // ---- round 3: coalesced segment processing ----
    for (int r = lo + tid; r < hi; r += NTHR) {
        int   n  = neuron_idx[r];
        float dv = d_vals[r];
        float z  = zlI[r];
        float v  = drow[n] * dv;
        float add = -z * v;
        if (v < 0.0f)      atomicAdd(&zl[n], add);
        else if (v > 0.0f) atomicAdd(&zu[n], add);
    }
    __syncthreads();

    // ---- full-slice write (covers zeros; no output pre-zero needed) ----
    const int N4 = N >> 2;
    const float4* zl4 = (const float4*)zl;
    const float4* zu4 = (const float4*)zu;
    float4* ozl = (float4*)(out + (size_t)b * N);
    float4* ozu = (float4*)(out + (size_t)(B + b) * N);
    if (N4 == (NTHR >> 1)) {           // fast path: N == 2048
        if (tid < N4) ozl[tid]       = zl4[tid];
        else          ozu[tid - N4]  = zu4[tid - N4];
    } else {
        for (int i = tid; i < N4; i += NTHR) { ozl[i] = zl4[i]; ozu[i] = zu4[i]; }
    }
}

extern "C" void kernel_launch(void* const* d_in, const int* in_sizes, int n_in,
                              void* d_out, int out_size, void* d_ws, size_t ws_size,
                              hipStream_t stream) {
    const int*   batch_idx  = (const int*)  d_in[0];
    const int*   neuron_idx = (const int*)  d_in[1];
    const float* d_vals     = (const float*)d_in[2];
    const float* d_next     = (const float*)d_in[3];
    const float* zlI        = (const float*)d_in[4];
    float*       out        = (float*)d_out;

    const int K = in_sizes[0];          // 32768
    const int B = 32;                   // reference constant
    const int N = in_sizes[3] / B;      // 2048
    const int S = (K + NTHR - 1) / NTHR; // probe stride (32) — refine handles S>64 via strided loop

    size_t lds_bytes = (size_t)3 * N * sizeof(float) + (NTHR + 4) * sizeof(int);
    dualrelu_kernel<<<dim3(B), dim3(NTHR), lds_bytes, stream>>>(
        batch_idx, neuron_idx, d_vals, d_next, zlI, out, K, B, N, S);
}